// Round 5
// baseline (4171.342 us; speedup 1.0000x reference)
//
#include <hip/hip_runtime.h>
#include <hip/hip_cooperative_groups.h>

namespace cg = cooperative_groups;

#define HS 501
#define VS 533
#define KP 512
#define NB 2048
#define MAXN 32
#define NVT 10

typedef short s16x8 __attribute__((ext_vector_type(8)));
typedef float f32x4 __attribute__((ext_vector_type(4)));

// ---- static device buffers (rewritten every launch before being read) ----
__device__ ushort  g_Wb1[3*KP*KP];      // [gate][h][k] bf16, zero-padded (planar 1536x512)
__device__ ushort  g_Wb2[2*KP*KP];      // [s][h][k]   (s=0:Wg, s=1:Wm)  (planar 1024x512)
__device__ ushort  g_Wf [128*KP];       // [j][k] rows 0..55=W1, 56..111=W2
__device__ float   g_giT[NVT*3*KP];     // [t][gate][h] = W_ih col t + b_ih
__device__ float   g_bhh[3*KP];
__device__ float   g_wgid[MAXN*KP];     // Wg[:,501+v]
__device__ float   g_wmid[MAXN*KP];     // Wm[:,501+v]
__device__ float   g_bgt[KP];
__device__ float   g_bias[128];
__device__ unsigned g_adjm[NB*MAXN];    // bit n = adj[b,n,v]
__device__ ushort  g_Hin[NB*KP];        // gathered GRU input H (bf16)
__device__ ushort  g_Hv [NB*KP];        // GRU output of current step (bf16)
__device__ ushort  g_gated[NB*MAXN*KP]; // cached gated rows (bf16)
__device__ int     g_adjfmt;            // 0=int32, 1=float32, 2=byte

__device__ __forceinline__ float b2f(ushort h){ return __uint_as_float(((unsigned)h)<<16); }
__device__ __forceinline__ ushort f2b(float f){
  unsigned u = __float_as_uint(f);
  u += 0x7FFFu + ((u>>16)&1u);
  return (ushort)(u>>16);
}
__device__ __forceinline__ float sigm(float x){ return 1.f/(1.f + __expf(-x)); }
__device__ __forceinline__ float tanh_f(float x){ return 1.f - 2.f/(1.f + __expf(2.f*x)); }

// ---------------- adj dtype detector ----------------
__global__ __launch_bounds__(256) void detect_adj(const void* __restrict__ adj){
  __shared__ int bad_i32, bad_f32;
  if (threadIdx.x == 0){ bad_i32 = 0; bad_f32 = 0; }
  __syncthreads();
  const int*   ai = (const int*)adj;
  const float* af = (const float*)adj;
  int li = 0, lf = 0;
  for (int i = threadIdx.x; i < 1024; i += 256){
    int w = ai[i];
    if (w != 0 && w != 1) li = 1;
    float f = af[i];
    if (f != 0.f && f != 1.f) lf = 1;
  }
  if (li) atomicOr(&bad_i32, 1);
  if (lf) atomicOr(&bad_f32, 1);
  __syncthreads();
  if (threadIdx.x == 0)
    g_adjfmt = (!bad_i32) ? 0 : (!bad_f32) ? 1 : 2;
}

// ---------------- setup kernels ----------------
__global__ __launch_bounds__(256) void prep_weights(const float* __restrict__ W_hh,
                                                    const float* __restrict__ Wg,
                                                    const float* __restrict__ Wm,
                                                    const float* __restrict__ W1,
                                                    const float* __restrict__ W2){
  int i = blockIdx.x*256 + threadIdx.x;
  const int NW1 = 3*KP*KP, NW2 = 2*KP*KP, NWF = 128*KP;
  if (i < NW1){
    int g = i >> 18; int rem = i & 0x3FFFF; int h = rem >> 9; int k = rem & 511;
    float v = (h < HS && k < HS) ? W_hh[(g*HS + h)*HS + k] : 0.f;
    g_Wb1[i] = f2b(v);
  } else if (i < NW1 + NW2){
    int j = i - NW1; int s = j >> 18; int rem = j & 0x3FFFF; int h = rem >> 9; int k = rem & 511;
    const float* src = s ? Wm : Wg;
    float v = (h < HS && k < HS) ? src[h*VS + k] : 0.f;
    g_Wb2[j] = f2b(v);
  } else if (i < NW1 + NW2 + NWF){
    int j = i - NW1 - NW2; int r = j >> 9; int k = j & 511;
    float v = 0.f;
    if (k < HS){
      if (r < 56) v = W1[r*HS + k];
      else if (r < 112) v = W2[(r-56)*HS + k];
    }
    g_Wf[j] = f2b(v);
  }
}

__global__ __launch_bounds__(256) void prep_tables(const float* __restrict__ W_ih,
                                                   const float* __restrict__ b_ih,
                                                   const float* __restrict__ b_hh,
                                                   const float* __restrict__ Wg,
                                                   const float* __restrict__ Wm,
                                                   const float* __restrict__ bg,
                                                   const float* __restrict__ b1,
                                                   const float* __restrict__ b2,
                                                   const void* __restrict__ adj){
  int i = blockIdx.x*256 + threadIdx.x;
  if (i < NVT*3*KP){
    int t = i / 1536; int rem = i - t*1536; int g = rem >> 9; int h = rem & 511;
    g_giT[i] = (h < HS) ? W_ih[(g*HS + h)*NVT + t] + b_ih[g*HS + h] : 0.f;
    return;
  }
  i -= NVT*3*KP;
  if (i < 3*KP){
    int g = i >> 9, h = i & 511;
    g_bhh[i] = (h < HS) ? b_hh[g*HS + h] : 0.f;
    return;
  }
  i -= 3*KP;
  if (i < MAXN*KP){
    int v = i >> 9, h = i & 511;
    g_wgid[i] = (h < HS) ? Wg[h*VS + HS + v] : 0.f;
    return;
  }
  i -= MAXN*KP;
  if (i < MAXN*KP){
    int v = i >> 9, h = i & 511;
    g_wmid[i] = (h < HS) ? Wm[h*VS + HS + v] : 0.f;
    return;
  }
  i -= MAXN*KP;
  if (i < KP){ g_bgt[i] = (i < HS) ? bg[i] : 0.f; return; }
  i -= KP;
  if (i < 128){ g_bias[i] = (i < 56) ? b1[i] : (i < 112) ? b2[i-56] : 0.f; return; }
  i -= 128;
  if (i < NB*MAXN){
    int b = i >> 5, v = i & 31;
    const int fmt = g_adjfmt;
    unsigned m = 0;
    const size_t base = (size_t)b*MAXN*MAXN + v;
    if (fmt == 0){
      const int* a = (const int*)adj;
      for (int n = 0; n < MAXN; ++n) if (a[base + (size_t)n*MAXN] != 0) m |= (1u << n);
    } else if (fmt == 1){
      const float* a = (const float*)adj;
      for (int n = 0; n < MAXN; ++n) if (a[base + (size_t)n*MAXN] != 0.f) m |= (1u << n);
    } else {
      const unsigned char* a = (const unsigned char*)adj;
      for (int n = 0; n < MAXN; ++n) if (a[base + (size_t)n*MAXN]) m |= (1u << n);
    }
    g_adjm[i] = m;
  }
}

// =============== cooperative kernel: whole 32-step recurrence ===============
// 256 blocks x 512 threads (1 block/CU, co-resident). Block (bx,by) owns
// rows [by*32,+32), cols [bx*128,+128). grid.sync() replaces kernel splits.
__global__ __launch_bounds__(512) void k_steps(const int* __restrict__ node_types,
                                               float* __restrict__ out){
  cg::grid_group grid = cg::this_grid();
  __shared__ float gv_s[32*128];   // 16 KB

  const int tid  = threadIdx.x;
  const int lane = tid & 63;
  const int w    = tid >> 6;      // 0..7
  const int wm   = w & 1;
  const int wn   = w >> 1;        // 0..3
  const int bx   = blockIdx.x & 3;
  const int by   = blockIdx.x >> 2;   // 0..63
  const int m0   = by*32 + wm*16;
  const int h0   = bx*128 + wn*32;
  const int lr   = lane & 15;
  const int lk   = lane >> 4;

  for (int v = 0; v < MAXN; ++v){
    // ---------------- phase A: gh = Hin @ W_hh^T (3 gates) + GRU -> g_Hv ----------------
    {
      f32x4 acc[2][3];
      #pragma unroll
      for (int nf = 0; nf < 2; ++nf)
        #pragma unroll
        for (int g = 0; g < 3; ++g) acc[nf][g] = (f32x4){0.f,0.f,0.f,0.f};

      if (v > 0){
        const ushort* Ap = g_Hin + (size_t)(m0 + lr)*KP + lk*8;
        const ushort* Bp = g_Wb1 + (size_t)(h0 + lr)*KP + lk*8;
        #pragma unroll
        for (int ks = 0; ks < 16; ++ks){
          s16x8 a0 = *(const s16x8*)(Ap + ks*32);
          #pragma unroll
          for (int nf = 0; nf < 2; ++nf){
            #pragma unroll
            for (int g = 0; g < 3; ++g){
              s16x8 b = *(const s16x8*)(Bp + (size_t)g*KP*KP + nf*16*KP + ks*32);
              acc[nf][g] = __builtin_amdgcn_mfma_f32_16x16x32_bf16(a0, b, acc[nf][g], 0, 0, 0);
            }
          }
        }
      }

      #pragma unroll
      for (int r = 0; r < 4; ++r){
        const int b = m0 + lk*4 + r;
        const int t = node_types[b*MAXN + v];
        #pragma unroll
        for (int nf = 0; nf < 2; ++nf){
          const int h = h0 + nf*16 + lr;
          const float gir = g_giT[(t*3 + 0)*KP + h];
          const float giz = g_giT[(t*3 + 1)*KP + h];
          const float gin = g_giT[(t*3 + 2)*KP + h];
          const float ghr = acc[nf][0][r] + g_bhh[0*KP + h];
          const float ghz = acc[nf][1][r] + g_bhh[1*KP + h];
          const float ghn = acc[nf][2][r] + g_bhh[2*KP + h];
          const float rr = sigm(gir + ghr);
          const float zz = sigm(giz + ghz);
          const float nn = tanh_f(gin + rr*ghn);
          const float hp = (v > 0) ? b2f(g_Hin[(size_t)b*KP + h]) : 0.f;
          const float hv = (1.f - zz)*nn + zz*hp;
          g_Hv[(size_t)b*KP + h] = (h < HS) ? f2b(hv) : (ushort)0;
        }
      }
    }
    grid.sync();

    if (v < MAXN - 1){
      // ------- phase B: gated = sig(Hv@Wg^T+..)*(Hv@Wm^T+..) + gather next Hin -------
      {
        f32x4 acc[2][2];
        #pragma unroll
        for (int nf = 0; nf < 2; ++nf)
          #pragma unroll
          for (int s = 0; s < 2; ++s) acc[nf][s] = (f32x4){0.f,0.f,0.f,0.f};

        const ushort* Ap = g_Hv  + (size_t)(m0 + lr)*KP + lk*8;
        const ushort* Bp = g_Wb2 + (size_t)(h0 + lr)*KP + lk*8;
        #pragma unroll
        for (int ks = 0; ks < 16; ++ks){
          s16x8 a0 = *(const s16x8*)(Ap + ks*32);
          #pragma unroll
          for (int nf = 0; nf < 2; ++nf){
            #pragma unroll
            for (int s = 0; s < 2; ++s){
              s16x8 b = *(const s16x8*)(Bp + (size_t)s*KP*KP + nf*16*KP + ks*32);
              acc[nf][s] = __builtin_amdgcn_mfma_f32_16x16x32_bf16(a0, b, acc[nf][s], 0, 0, 0);
            }
          }
        }

        #pragma unroll
        for (int r = 0; r < 4; ++r){
          const int b = m0 + lk*4 + r;
          #pragma unroll
          for (int nf = 0; nf < 2; ++nf){
            const int h = h0 + nf*16 + lr;
            const float sg = sigm(acc[nf][0][r] + g_bgt[h] + g_wgid[v*KP + h]);
            const float mg = acc[nf][1][r] + g_wmid[v*KP + h];
            float gv = sg * mg;
            if (h >= HS) gv = 0.f;
            g_gated[((size_t)b*MAXN + v)*KP + h] = f2b(gv);
            gv_s[(wm*16 + lk*4 + r)*128 + (wn*32 + nf*16 + lr)] = gv;
          }
        }
      }
      __syncthreads();

      {
        // 32 rows x 128 cols = 4096 outputs; 512 threads x 8 cols each.
        // Reads only data this block wrote (gv_s now, g_gated in prior steps).
        const int row = tid >> 4;
        const int c8  = (tid & 15) * 8;
        const int b   = by*32 + row;
        const int hb  = bx*128 + c8;
        unsigned m = g_adjm[b*MAXN + v + 1];
        float a8[8] = {0.f,0.f,0.f,0.f,0.f,0.f,0.f,0.f};
        while (m){
          const int n = __builtin_ctz(m); m &= m - 1;
          if (n == v){
            #pragma unroll
            for (int j = 0; j < 8; ++j) a8[j] += gv_s[row*128 + c8 + j];
          } else {
            s16x8 gvv = *(const s16x8*)(g_gated + ((size_t)b*MAXN + n)*KP + hb);
            #pragma unroll
            for (int j = 0; j < 8; ++j) a8[j] += b2f((ushort)gvv[j]);
          }
        }
        s16x8 o;
        #pragma unroll
        for (int j = 0; j < 8; ++j) o[j] = (short)f2b(a8[j]);
        *(s16x8*)(g_Hin + (size_t)b*KP + hb) = o;
      }
      grid.sync();
    } else {
      // ---------------- final: mu/logvar = Hv(31) @ [W1;W2]^T + b ----------------
      if (bx == 0){
        for (int t = w; t < 14; t += 8){
          const int fm = t / 7;        // row-frag 0..1
          const int fc = t % 7;        // col-frag 0..6 (112 cols)
          const ushort* Ap = g_Hv + (size_t)(by*32 + fm*16 + lr)*KP + lk*8;
          const ushort* Bp = g_Wf + (size_t)(fc*16 + lr)*KP + lk*8;
          f32x4 acc = (f32x4){0.f,0.f,0.f,0.f};
          #pragma unroll
          for (int ks = 0; ks < 16; ++ks){
            s16x8 a0 = *(const s16x8*)(Ap + ks*32);
            s16x8 b0 = *(const s16x8*)(Bp + ks*32);
            acc = __builtin_amdgcn_mfma_f32_16x16x32_bf16(a0, b0, acc, 0, 0, 0);
          }
          #pragma unroll
          for (int r = 0; r < 4; ++r){
            const int b = by*32 + fm*16 + lk*4 + r;
            const int j = fc*16 + lr;
            const float val = acc[r] + g_bias[j];
            if (j < 56)       out[(size_t)b*56 + j] = val;
            else if (j < 112) out[(size_t)NB*56 + (size_t)b*56 + (j - 56)] = val;
          }
        }
      }
    }
  }
}

extern "C" void kernel_launch(void* const* d_in, const int* in_sizes, int n_in,
                              void* d_out, int out_size, void* d_ws, size_t ws_size,
                              hipStream_t stream){
  const int*   node_types = (const int*)d_in[0];
  const void*  adj        = (const void*)d_in[1];
  const float* W_ih       = (const float*)d_in[2];
  const float* W_hh       = (const float*)d_in[3];
  const float* b_ih       = (const float*)d_in[4];
  const float* b_hh       = (const float*)d_in[5];
  const float* Wg         = (const float*)d_in[6];
  const float* bg         = (const float*)d_in[7];
  const float* Wm         = (const float*)d_in[8];
  const float* W1         = (const float*)d_in[9];
  const float* b1         = (const float*)d_in[10];
  const float* W2         = (const float*)d_in[11];
  const float* b2         = (const float*)d_in[12];
  float* out = (float*)d_out;

  const int NPREP1 = 3*KP*KP + 2*KP*KP + 128*KP;
  const int NPREP2 = NVT*3*KP + 3*KP + 2*MAXN*KP + KP + 128 + NB*MAXN;

  detect_adj  <<<1, 256, 0, stream>>>(adj);
  prep_weights<<<(NPREP1 + 255)/256, 256, 0, stream>>>(W_hh, Wg, Wm, W1, W2);
  prep_tables <<<(NPREP2 + 255)/256, 256, 0, stream>>>(W_ih, b_ih, b_hh, Wg, Wm, bg, b1, b2, adj);

  void* kargs[] = { (void*)&node_types, (void*)&out };
  hipLaunchCooperativeKernel((void*)k_steps, dim3(256), dim3(512), kargs, 0, stream);
}

// Round 7
// 2821.474 us; speedup vs baseline: 1.4784x; 1.4784x over previous
//
#include <hip/hip_runtime.h>
#include <hip/hip_cooperative_groups.h>

namespace cg = cooperative_groups;

#define HS 501
#define VS 533
#define KP 512
#define NB 2048
#define MAXN 32
#define NVT 10

typedef short s16x8 __attribute__((ext_vector_type(8)));
typedef float f32x4 __attribute__((ext_vector_type(4)));

// ---- static device buffers (rewritten every launch before being read) ----
__device__ ushort  g_Wb1[3*KP*KP];      // [gate][h][k] bf16, zero-padded (planar 1536x512)
__device__ ushort  g_Wb2[2*KP*KP];      // [s][h][k]   (s=0:Wg, s=1:Wm)  (planar 1024x512)
__device__ ushort  g_Wf [128*KP];       // [j][k] rows 0..55=W1, 56..111=W2
__device__ float   g_giT[NVT*3*KP];     // [t][gate][h] = W_ih col t + b_ih
__device__ float   g_bhh[3*KP];
__device__ float   g_wgid[MAXN*KP];     // Wg[:,501+v]
__device__ float   g_wmid[MAXN*KP];     // Wm[:,501+v]
__device__ float   g_bgt[KP];
__device__ float   g_bias[128];
__device__ unsigned g_adjm[NB*MAXN];    // bit n = adj[b,n,v]
__device__ ushort  g_Hin[NB*KP];        // gathered GRU input H (bf16)
__device__ ushort  g_Hv [NB*KP];        // GRU output of current step (bf16)
__device__ ushort  g_gated[NB*MAXN*KP]; // cached gated rows (bf16)
__device__ int     g_adjfmt;            // 0=int32, 1=float32, 2=byte

__device__ __forceinline__ float b2f(ushort h){ return __uint_as_float(((unsigned)h)<<16); }
__device__ __forceinline__ ushort f2b(float f){
  unsigned u = __float_as_uint(f);
  u += 0x7FFFu + ((u>>16)&1u);
  return (ushort)(u>>16);
}
__device__ __forceinline__ float sigm(float x){ return 1.f/(1.f + __expf(-x)); }
__device__ __forceinline__ float tanh_f(float x){ return 1.f - 2.f/(1.f + __expf(2.f*x)); }

// ---------------- adj dtype detector ----------------
__global__ __launch_bounds__(256) void detect_adj(const void* __restrict__ adj){
  __shared__ int bad_i32, bad_f32;
  if (threadIdx.x == 0){ bad_i32 = 0; bad_f32 = 0; }
  __syncthreads();
  const int*   ai = (const int*)adj;
  const float* af = (const float*)adj;
  int li = 0, lf = 0;
  for (int i = threadIdx.x; i < 1024; i += 256){
    int w = ai[i];
    if (w != 0 && w != 1) li = 1;
    float f = af[i];
    if (f != 0.f && f != 1.f) lf = 1;
  }
  if (li) atomicOr(&bad_i32, 1);
  if (lf) atomicOr(&bad_f32, 1);
  __syncthreads();
  if (threadIdx.x == 0)
    g_adjfmt = (!bad_i32) ? 0 : (!bad_f32) ? 1 : 2;
}

// ---------------- setup kernels ----------------
__global__ __launch_bounds__(256) void prep_weights(const float* __restrict__ W_hh,
                                                    const float* __restrict__ Wg,
                                                    const float* __restrict__ Wm,
                                                    const float* __restrict__ W1,
                                                    const float* __restrict__ W2){
  int i = blockIdx.x*256 + threadIdx.x;
  const int NW1 = 3*KP*KP, NW2 = 2*KP*KP, NWF = 128*KP;
  if (i < NW1){
    int g = i >> 18; int rem = i & 0x3FFFF; int h = rem >> 9; int k = rem & 511;
    float v = (h < HS && k < HS) ? W_hh[(g*HS + h)*HS + k] : 0.f;
    g_Wb1[i] = f2b(v);
  } else if (i < NW1 + NW2){
    int j = i - NW1; int s = j >> 18; int rem = j & 0x3FFFF; int h = rem >> 9; int k = rem & 511;
    const float* src = s ? Wm : Wg;
    float v = (h < HS && k < HS) ? src[h*VS + k] : 0.f;
    g_Wb2[j] = f2b(v);
  } else if (i < NW1 + NW2 + NWF){
    int j = i - NW1 - NW2; int r = j >> 9; int k = j & 511;
    float v = 0.f;
    if (k < HS){
      if (r < 56) v = W1[r*HS + k];
      else if (r < 112) v = W2[(r-56)*HS + k];
    }
    g_Wf[j] = f2b(v);
  }
}

__global__ __launch_bounds__(256) void prep_tables(const float* __restrict__ W_ih,
                                                   const float* __restrict__ b_ih,
                                                   const float* __restrict__ b_hh,
                                                   const float* __restrict__ Wg,
                                                   const float* __restrict__ Wm,
                                                   const float* __restrict__ bg,
                                                   const float* __restrict__ b1,
                                                   const float* __restrict__ b2,
                                                   const void* __restrict__ adj){
  int i = blockIdx.x*256 + threadIdx.x;
  if (i < NVT*3*KP){
    int t = i / 1536; int rem = i - t*1536; int g = rem >> 9; int h = rem & 511;
    g_giT[i] = (h < HS) ? W_ih[(g*HS + h)*NVT + t] + b_ih[g*HS + h] : 0.f;
    return;
  }
  i -= NVT*3*KP;
  if (i < 3*KP){
    int g = i >> 9, h = i & 511;
    g_bhh[i] = (h < HS) ? b_hh[g*HS + h] : 0.f;
    return;
  }
  i -= 3*KP;
  if (i < MAXN*KP){
    int v = i >> 9, h = i & 511;
    g_wgid[i] = (h < HS) ? Wg[h*VS + HS + v] : 0.f;
    return;
  }
  i -= MAXN*KP;
  if (i < MAXN*KP){
    int v = i >> 9, h = i & 511;
    g_wmid[i] = (h < HS) ? Wm[h*VS + HS + v] : 0.f;
    return;
  }
  i -= MAXN*KP;
  if (i < KP){ g_bgt[i] = (i < HS) ? bg[i] : 0.f; return; }
  i -= KP;
  if (i < 128){ g_bias[i] = (i < 56) ? b1[i] : (i < 112) ? b2[i-56] : 0.f; return; }
  i -= 128;
  if (i < NB*MAXN){
    int b = i >> 5, v = i & 31;
    const int fmt = g_adjfmt;
    unsigned m = 0;
    const size_t base = (size_t)b*MAXN*MAXN + v;
    if (fmt == 0){
      const int* a = (const int*)adj;
      for (int n = 0; n < MAXN; ++n) if (a[base + (size_t)n*MAXN] != 0) m |= (1u << n);
    } else if (fmt == 1){
      const float* a = (const float*)adj;
      for (int n = 0; n < MAXN; ++n) if (a[base + (size_t)n*MAXN] != 0.f) m |= (1u << n);
    } else {
      const unsigned char* a = (const unsigned char*)adj;
      for (int n = 0; n < MAXN; ++n) if (a[base + (size_t)n*MAXN]) m |= (1u << n);
    }
    g_adjm[i] = m;
  }
}

// =============== cooperative kernel, XCD-local layout, grid.sync ===============
// 256 blocks x 512 threads (1/CU, co-resident). Group grp=blockIdx&7 (one XCD
// under round-robin dispatch; correctness doesn't depend on it) owns rows
// [grp*256,+256). Col-slice J=blockIdx>>3 owns h-cols [J*16,+16) across all
// gates/planes -> every epilogue is block-local. W_hh + Wg/Wm slices in LDS.
__global__ __launch_bounds__(512) void k_steps(const int* __restrict__ node_types,
                                               float* __restrict__ out){
  cg::grid_group grid = cg::this_grid();
  __shared__ ushort sW1[48*512];   // 48 KB: [gate*16+col][k], XOR-swizzled
  __shared__ ushort sW2[32*512];   // 32 KB: [plane*16+col][k], XOR-swizzled
  __shared__ ushort sGt[256*16];   // 8 KB: current-step gated (stripe x own cols)

  const int tid  = threadIdx.x;
  const int lane = tid & 63;
  const int w    = tid >> 6;        // wave 0..7
  const int lr   = lane & 15;
  const int lk   = lane >> 4;
  const int grp  = blockIdx.x & 7;
  const int J    = blockIdx.x >> 3; // 0..31
  const int c0   = J*16;
  const int rb   = grp*256;
  const int rf0  = w*2;             // this wave's two row-fragments

  // ---- prologue: stage W_hh slice (48 rows) + Wg/Wm slice (32 rows) into LDS ----
  for (int idx = tid; idx < 80*64; idx += 512){
    const int r = idx >> 6, c = idx & 63;
    if (r < 48){
      const int gt = r >> 4, col = r & 15;
      s16x8 x = *(const s16x8*)(g_Wb1 + (size_t)(gt*KP + c0 + col)*KP + c*8);
      *(s16x8*)((char*)sW1 + r*1024 + ((c*16) ^ ((r & 7) << 4))) = x;
    } else {
      const int r2 = r - 48;
      const int pl = r2 >> 4, col = r2 & 15;
      s16x8 x = *(const s16x8*)(g_Wb2 + (size_t)(pl*KP + c0 + col)*KP + c*8);
      *(s16x8*)((char*)sW2 + r2*1024 + ((c*16) ^ ((r2 & 7) << 4))) = x;
    }
  }
  __syncthreads();

  for (int v = 0; v < MAXN; ++v){
    // ================= phase A: GEMM1 (3 gates, own 16 cols) + GRU =================
    {
      f32x4 acc[2][3];
      #pragma unroll
      for (int rr = 0; rr < 2; ++rr)
        #pragma unroll
        for (int g = 0; g < 3; ++g) acc[rr][g] = (f32x4){0.f,0.f,0.f,0.f};

      if (v > 0){
        const ushort* Ab = g_Hin + (size_t)(rb + rf0*16 + lr)*KP + lk*8;
        #pragma unroll 4
        for (int ks = 0; ks < 16; ++ks){
          s16x8 a0 = *(const s16x8*)(Ab + ks*32);
          s16x8 a1 = *(const s16x8*)(Ab + 16*KP + ks*32);
          #pragma unroll
          for (int g = 0; g < 3; ++g){
            s16x8 bf = *(const s16x8*)((const char*)sW1 + (g*16 + lr)*1024
                        + ((ks*64 + lk*16) ^ ((lr & 7) << 4)));
            acc[0][g] = __builtin_amdgcn_mfma_f32_16x16x32_bf16(a0, bf, acc[0][g], 0, 0, 0);
            acc[1][g] = __builtin_amdgcn_mfma_f32_16x16x32_bf16(a1, bf, acc[1][g], 0, 0, 0);
          }
        }
      }

      const int h = c0 + lr;
      const float gbr = g_bhh[0*KP + h];
      const float gbz = g_bhh[1*KP + h];
      const float gbn = g_bhh[2*KP + h];
      #pragma unroll
      for (int rr = 0; rr < 2; ++rr){
        #pragma unroll
        for (int r = 0; r < 4; ++r){
          const int row = rb + (rf0 + rr)*16 + lk*4 + r;
          const int t = node_types[row*MAXN + v];
          const float gir = g_giT[(t*3 + 0)*KP + h];
          const float giz = g_giT[(t*3 + 1)*KP + h];
          const float gin = g_giT[(t*3 + 2)*KP + h];
          const float rg = sigm(gir + acc[rr][0][r] + gbr);
          const float zg = sigm(giz + acc[rr][1][r] + gbz);
          const float ng = tanh_f(gin + rg*(acc[rr][2][r] + gbn));
          const float hp = (v > 0) ? b2f(g_Hin[(size_t)row*KP + h]) : 0.f;
          const float hv = (1.f - zg)*ng + zg*hp;
          g_Hv[(size_t)row*KP + h] = (h < HS) ? f2b(hv) : (ushort)0;
        }
      }
    }
    grid.sync();   // Hv complete

    if (v < MAXN - 1){
      // ============ phase B: GEMM2 (Wg/Wm own 16 cols) + gated + gather ============
      {
        f32x4 acc[2][2];
        #pragma unroll
        for (int rr = 0; rr < 2; ++rr)
          #pragma unroll
          for (int s = 0; s < 2; ++s) acc[rr][s] = (f32x4){0.f,0.f,0.f,0.f};

        const ushort* Ab = g_Hv + (size_t)(rb + rf0*16 + lr)*KP + lk*8;
        #pragma unroll 4
        for (int ks = 0; ks < 16; ++ks){
          s16x8 a0 = *(const s16x8*)(Ab + ks*32);
          s16x8 a1 = *(const s16x8*)(Ab + 16*KP + ks*32);
          s16x8 b0 = *(const s16x8*)((const char*)sW2 + (0*16 + lr)*1024
                      + ((ks*64 + lk*16) ^ ((lr & 7) << 4)));
          s16x8 b1 = *(const s16x8*)((const char*)sW2 + (16 + lr)*1024
                      + ((ks*64 + lk*16) ^ (((16 + lr) & 7) << 4)));
          acc[0][0] = __builtin_amdgcn_mfma_f32_16x16x32_bf16(a0, b0, acc[0][0], 0, 0, 0);
          acc[0][1] = __builtin_amdgcn_mfma_f32_16x16x32_bf16(a0, b1, acc[0][1], 0, 0, 0);
          acc[1][0] = __builtin_amdgcn_mfma_f32_16x16x32_bf16(a1, b0, acc[1][0], 0, 0, 0);
          acc[1][1] = __builtin_amdgcn_mfma_f32_16x16x32_bf16(a1, b1, acc[1][1], 0, 0, 0);
        }

        const int h = c0 + lr;
        const float bgh = g_bgt[h] + g_wgid[v*KP + h];
        const float bmh = g_wmid[v*KP + h];
        #pragma unroll
        for (int rr = 0; rr < 2; ++rr){
          #pragma unroll
          for (int r = 0; r < 4; ++r){
            const int lrow = (rf0 + rr)*16 + lk*4 + r;
            const int row = rb + lrow;
            const float sg = sigm(acc[rr][0][r] + bgh);
            const float mg = acc[rr][1][r] + bmh;
            float gv = sg * mg;
            if (h >= HS) gv = 0.f;
            const ushort gvb = f2b(gv);
            g_gated[((size_t)row*MAXN + v)*KP + h] = gvb;
            sGt[lrow*16 + lr] = gvb;
          }
        }
      }
      __syncthreads();

      {
        // gather next Hin: 512 threads = 256 rows x 2 col-halves (8 cols, 16B)
        const int l    = tid >> 1;
        const int half = tid & 1;
        const int row  = rb + l;
        const int hb   = c0 + half*8;
        unsigned m = g_adjm[row*MAXN + v + 1];
        float a8[8] = {0.f,0.f,0.f,0.f,0.f,0.f,0.f,0.f};
        while (m){
          const int n = __builtin_ctz(m); m &= m - 1;
          s16x8 x;
          if (n == v) x = *(const s16x8*)(sGt + l*16 + half*8);
          else        x = *(const s16x8*)(g_gated + ((size_t)row*MAXN + n)*KP + hb);
          #pragma unroll
          for (int j = 0; j < 8; ++j) a8[j] += b2f((ushort)x[j]);
        }
        s16x8 o;
        #pragma unroll
        for (int j = 0; j < 8; ++j) o[j] = (short)f2b(a8[j]);
        *(s16x8*)(g_Hin + (size_t)row*KP + hb) = o;
      }
      grid.sync();   // Hin complete
    } else {
      // ============ final: mu/logvar = Hv(31) @ [W1;W2]^T + b ============
      if (w < 4){
        const int rf = J & 15;       // row-fragment of this group's stripe
        const int cf = (J >> 4)*4 + w;
        if (cf < 7){
          const ushort* Ab = g_Hv + (size_t)(rb + rf*16 + lr)*KP + lk*8;
          const ushort* Bb = g_Wf + (size_t)(cf*16 + lr)*KP + lk*8;
          f32x4 acc = (f32x4){0.f,0.f,0.f,0.f};
          #pragma unroll 4
          for (int ks = 0; ks < 16; ++ks){
            s16x8 a0 = *(const s16x8*)(Ab + ks*32);
            s16x8 b0 = *(const s16x8*)(Bb + ks*32);
            acc = __builtin_amdgcn_mfma_f32_16x16x32_bf16(a0, b0, acc, 0, 0, 0);
          }
          const int j2 = cf*16 + lr;
          #pragma unroll
          for (int r = 0; r < 4; ++r){
            const int row = rb + rf*16 + lk*4 + r;
            const float val = acc[r] + g_bias[j2];
            if (j2 < 56)       out[(size_t)row*56 + j2] = val;
            else if (j2 < 112) out[(size_t)NB*56 + (size_t)row*56 + (j2 - 56)] = val;
          }
        }
      }
    }
  }
}

extern "C" void kernel_launch(void* const* d_in, const int* in_sizes, int n_in,
                              void* d_out, int out_size, void* d_ws, size_t ws_size,
                              hipStream_t stream){
  const int*   node_types = (const int*)d_in[0];
  const void*  adj        = (const void*)d_in[1];
  const float* W_ih       = (const float*)d_in[2];
  const float* W_hh       = (const float*)d_in[3];
  const float* b_ih       = (const float*)d_in[4];
  const float* b_hh       = (const float*)d_in[5];
  const float* Wg         = (const float*)d_in[6];
  const float* bg         = (const float*)d_in[7];
  const float* Wm         = (const float*)d_in[8];
  const float* W1         = (const float*)d_in[9];
  const float* b1         = (const float*)d_in[10];
  const float* W2         = (const float*)d_in[11];
  const float* b2         = (const float*)d_in[12];
  float* out = (float*)d_out;

  const int NPREP1 = 3*KP*KP + 2*KP*KP + 128*KP;
  const int NPREP2 = NVT*3*KP + 3*KP + 2*MAXN*KP + KP + 128 + NB*MAXN;

  detect_adj  <<<1, 256, 0, stream>>>(adj);
  prep_weights<<<(NPREP1 + 255)/256, 256, 0, stream>>>(W_hh, Wg, Wm, W1, W2);
  prep_tables <<<(NPREP2 + 255)/256, 256, 0, stream>>>(W_ih, b_ih, b_hh, Wg, Wm, bg, b1, b2, adj);

  void* kargs[] = { (void*)&node_types, (void*)&out };
  hipLaunchCooperativeKernel((void*)k_steps, dim3(256), dim3(512), kargs, 0, stream);
}

// Round 8
// 1535.401 us; speedup vs baseline: 2.7168x; 1.8376x over previous
//
#include <hip/hip_runtime.h>

#define HS 501
#define VS 533
#define KP 512
#define NB 2048
#define MAXN 32
#define NVT 10

typedef short s16x8 __attribute__((ext_vector_type(8)));
typedef float f32x4 __attribute__((ext_vector_type(4)));

// ---- static device buffers (rewritten every launch before being read) ----
__device__ ushort  g_Wb1[3*KP*KP];      // [gate][h][k] bf16, zero-padded (planar 1536x512)
__device__ ushort  g_Wb2[2*KP*KP];      // [s][h][k]   (s=0:Wg, s=1:Wm)  (planar 1024x512)
__device__ ushort  g_Wf [128*KP];       // [j][k] rows 0..55=W1, 56..111=W2
__device__ float   g_giT[NVT*3*KP];     // [t][gate][h] = W_ih col t + b_ih
__device__ float   g_bhh[3*KP];
__device__ float   g_wgid[MAXN*KP];     // Wg[:,501+v]
__device__ float   g_wmid[MAXN*KP];     // Wm[:,501+v]
__device__ float   g_bgt[KP];
__device__ float   g_bias[128];
__device__ unsigned g_adjm[NB*MAXN];    // bit n = adj[b,n,v]
__device__ ushort  g_Hin[NB*KP];        // gathered GRU input H (bf16)
__device__ ushort  g_Hv [NB*KP];        // GRU output of current step (bf16)
__device__ ushort  g_gated[NB*MAXN*KP]; // cached gated rows (bf16)
__device__ int     g_adjfmt;            // 0=int32, 1=float32, 2=byte

// per-group barrier counters, one cacheline each (avoid cross-group ping-pong)
struct alignas(128) BarCtr { unsigned c; unsigned pad[31]; };
__device__ BarCtr  g_barp[8];

__device__ __forceinline__ float b2f(ushort h){ return __uint_as_float(((unsigned)h)<<16); }
__device__ __forceinline__ ushort f2b(float f){
  unsigned u = __float_as_uint(f);
  u += 0x7FFFu + ((u>>16)&1u);
  return (ushort)(u>>16);
}
__device__ __forceinline__ float sigm(float x){ return 1.f/(1.f + __expf(-x)); }
__device__ __forceinline__ float tanh_f(float x){ return 1.f - 2.f/(1.f + __expf(2.f*x)); }

// ---------------- adj dtype detector + barrier reset ----------------
__global__ __launch_bounds__(256) void detect_adj(const void* __restrict__ adj){
  __shared__ int bad_i32, bad_f32;
  if (threadIdx.x == 0){ bad_i32 = 0; bad_f32 = 0; }
  if (threadIdx.x < 8) g_barp[threadIdx.x].c = 0u;
  __syncthreads();
  const int*   ai = (const int*)adj;
  const float* af = (const float*)adj;
  int li = 0, lf = 0;
  for (int i = threadIdx.x; i < 1024; i += 256){
    int w = ai[i];
    if (w != 0 && w != 1) li = 1;
    float f = af[i];
    if (f != 0.f && f != 1.f) lf = 1;
  }
  if (li) atomicOr(&bad_i32, 1);
  if (lf) atomicOr(&bad_f32, 1);
  __syncthreads();
  if (threadIdx.x == 0)
    g_adjfmt = (!bad_i32) ? 0 : (!bad_f32) ? 1 : 2;
}

// ---------------- setup kernels ----------------
__global__ __launch_bounds__(256) void prep_weights(const float* __restrict__ W_hh,
                                                    const float* __restrict__ Wg,
                                                    const float* __restrict__ Wm,
                                                    const float* __restrict__ W1,
                                                    const float* __restrict__ W2){
  int i = blockIdx.x*256 + threadIdx.x;
  const int NW1 = 3*KP*KP, NW2 = 2*KP*KP, NWF = 128*KP;
  if (i < NW1){
    int g = i >> 18; int rem = i & 0x3FFFF; int h = rem >> 9; int k = rem & 511;
    float v = (h < HS && k < HS) ? W_hh[(g*HS + h)*HS + k] : 0.f;
    g_Wb1[i] = f2b(v);
  } else if (i < NW1 + NW2){
    int j = i - NW1; int s = j >> 18; int rem = j & 0x3FFFF; int h = rem >> 9; int k = rem & 511;
    const float* src = s ? Wm : Wg;
    float v = (h < HS && k < HS) ? src[h*VS + k] : 0.f;
    g_Wb2[j] = f2b(v);
  } else if (i < NW1 + NW2 + NWF){
    int j = i - NW1 - NW2; int r = j >> 9; int k = j & 511;
    float v = 0.f;
    if (k < HS){
      if (r < 56) v = W1[r*HS + k];
      else if (r < 112) v = W2[(r-56)*HS + k];
    }
    g_Wf[j] = f2b(v);
  }
}

__global__ __launch_bounds__(256) void prep_tables(const float* __restrict__ W_ih,
                                                   const float* __restrict__ b_ih,
                                                   const float* __restrict__ b_hh,
                                                   const float* __restrict__ Wg,
                                                   const float* __restrict__ Wm,
                                                   const float* __restrict__ bg,
                                                   const float* __restrict__ b1,
                                                   const float* __restrict__ b2,
                                                   const void* __restrict__ adj){
  int i = blockIdx.x*256 + threadIdx.x;
  if (i < NVT*3*KP){
    int t = i / 1536; int rem = i - t*1536; int g = rem >> 9; int h = rem & 511;
    g_giT[i] = (h < HS) ? W_ih[(g*HS + h)*NVT + t] + b_ih[g*HS + h] : 0.f;
    return;
  }
  i -= NVT*3*KP;
  if (i < 3*KP){
    int g = i >> 9, h = i & 511;
    g_bhh[i] = (h < HS) ? b_hh[g*HS + h] : 0.f;
    return;
  }
  i -= 3*KP;
  if (i < MAXN*KP){
    int v = i >> 9, h = i & 511;
    g_wgid[i] = (h < HS) ? Wg[h*VS + HS + v] : 0.f;
    return;
  }
  i -= MAXN*KP;
  if (i < MAXN*KP){
    int v = i >> 9, h = i & 511;
    g_wmid[i] = (h < HS) ? Wm[h*VS + HS + v] : 0.f;
    return;
  }
  i -= MAXN*KP;
  if (i < KP){ g_bgt[i] = (i < HS) ? bg[i] : 0.f; return; }
  i -= KP;
  if (i < 128){ g_bias[i] = (i < 56) ? b1[i] : (i < 112) ? b2[i-56] : 0.f; return; }
  i -= 128;
  if (i < NB*MAXN){
    int b = i >> 5, v = i & 31;
    const int fmt = g_adjfmt;
    unsigned m = 0;
    const size_t base = (size_t)b*MAXN*MAXN + v;
    if (fmt == 0){
      const int* a = (const int*)adj;
      for (int n = 0; n < MAXN; ++n) if (a[base + (size_t)n*MAXN] != 0) m |= (1u << n);
    } else if (fmt == 1){
      const float* a = (const float*)adj;
      for (int n = 0; n < MAXN; ++n) if (a[base + (size_t)n*MAXN] != 0.f) m |= (1u << n);
    } else {
      const unsigned char* a = (const unsigned char*)adj;
      for (int n = 0; n < MAXN; ++n) if (a[base + (size_t)n*MAXN]) m |= (1u << n);
    }
    g_adjm[i] = m;
  }
}

// =============== cooperative kernel, XCD-local layout, per-group barriers ===============
// 256 blocks x 512 threads (1/CU, co-resident via cooperative launch). Group
// grp=blockIdx&7 owns rows [grp*256,+256); groups share NO data, so sync is
// per-group (32 blocks) with agent-scope release/acquire — correct regardless
// of block->XCD placement, fast when placement round-robins. Col-slice
// J=blockIdx>>3 owns h-cols [J*16,+16) across all gates/planes -> every
// epilogue is block-local. W_hh + Wg/Wm slices live in LDS.
__global__ __launch_bounds__(512) void k_steps(const int* __restrict__ node_types,
                                               float* __restrict__ out){
  __shared__ ushort sW1[48*512];   // 48 KB: [gate*16+col][k], XOR-swizzled
  __shared__ ushort sW2[32*512];   // 32 KB: [plane*16+col][k], XOR-swizzled
  __shared__ ushort sGt[256*16];   // 8 KB: current-step gated (stripe x own cols)

  const int tid  = threadIdx.x;
  const int lane = tid & 63;
  const int w    = tid >> 6;        // wave 0..7
  const int lr   = lane & 15;
  const int lk   = lane >> 4;
  const int grp  = blockIdx.x & 7;
  const int J    = blockIdx.x >> 3; // 0..31
  const int c0   = J*16;
  const int rb   = grp*256;
  const int rf0  = w*2;             // this wave's two row-fragments

  // ---- prologue: stage W_hh slice (48 rows) + Wg/Wm slice (32 rows) into LDS ----
  for (int idx = tid; idx < 80*64; idx += 512){
    const int r = idx >> 6, c = idx & 63;
    if (r < 48){
      const int gt = r >> 4, col = r & 15;
      s16x8 x = *(const s16x8*)(g_Wb1 + (size_t)(gt*KP + c0 + col)*KP + c*8);
      *(s16x8*)((char*)sW1 + r*1024 + ((c*16) ^ ((r & 7) << 4))) = x;
    } else {
      const int r2 = r - 48;
      const int pl = r2 >> 4, col = r2 & 15;
      s16x8 x = *(const s16x8*)(g_Wb2 + (size_t)(pl*KP + c0 + col)*KP + c*8);
      *(s16x8*)((char*)sW2 + r2*1024 + ((c*16) ^ ((r2 & 7) << 4))) = x;
    }
  }
  __syncthreads();

  unsigned ep = 0;  // barrier epoch (uniform across block)

  for (int v = 0; v < MAXN; ++v){
    // ================= phase A: GEMM1 (3 gates, own 16 cols) + GRU =================
    {
      f32x4 acc[2][3];
      #pragma unroll
      for (int rr = 0; rr < 2; ++rr)
        #pragma unroll
        for (int g = 0; g < 3; ++g) acc[rr][g] = (f32x4){0.f,0.f,0.f,0.f};

      if (v > 0){
        const ushort* Ab = g_Hin + (size_t)(rb + rf0*16 + lr)*KP + lk*8;
        #pragma unroll 4
        for (int ks = 0; ks < 16; ++ks){
          s16x8 a0 = *(const s16x8*)(Ab + ks*32);
          s16x8 a1 = *(const s16x8*)(Ab + 16*KP + ks*32);
          #pragma unroll
          for (int g = 0; g < 3; ++g){
            s16x8 bf = *(const s16x8*)((const char*)sW1 + (g*16 + lr)*1024
                        + ((ks*64 + lk*16) ^ ((lr & 7) << 4)));
            acc[0][g] = __builtin_amdgcn_mfma_f32_16x16x32_bf16(a0, bf, acc[0][g], 0, 0, 0);
            acc[1][g] = __builtin_amdgcn_mfma_f32_16x16x32_bf16(a1, bf, acc[1][g], 0, 0, 0);
          }
        }
      }

      const int h = c0 + lr;
      const float gbr = g_bhh[0*KP + h];
      const float gbz = g_bhh[1*KP + h];
      const float gbn = g_bhh[2*KP + h];
      #pragma unroll
      for (int rr = 0; rr < 2; ++rr){
        #pragma unroll
        for (int r = 0; r < 4; ++r){
          const int row = rb + (rf0 + rr)*16 + lk*4 + r;
          const int t = node_types[row*MAXN + v];
          const float gir = g_giT[(t*3 + 0)*KP + h];
          const float giz = g_giT[(t*3 + 1)*KP + h];
          const float gin = g_giT[(t*3 + 2)*KP + h];
          const float rg = sigm(gir + acc[rr][0][r] + gbr);
          const float zg = sigm(giz + acc[rr][1][r] + gbz);
          const float ng = tanh_f(gin + rg*(acc[rr][2][r] + gbn));
          const float hp = (v > 0) ? b2f(g_Hin[(size_t)row*KP + h]) : 0.f;
          const float hv = (1.f - zg)*ng + zg*hp;
          g_Hv[(size_t)row*KP + h] = (h < HS) ? f2b(hv) : (ushort)0;
        }
      }
    }
    // ---- group barrier: Hv complete for the stripe ----
    __syncthreads();
    ++ep;
    if (tid == 0){
      __hip_atomic_fetch_add(&g_barp[grp].c, 1u, __ATOMIC_RELEASE, __HIP_MEMORY_SCOPE_AGENT);
      const unsigned tgt = ep*32u;
      while (__hip_atomic_load(&g_barp[grp].c, __ATOMIC_ACQUIRE, __HIP_MEMORY_SCOPE_AGENT) < tgt)
        __builtin_amdgcn_s_sleep(1);
    }
    __syncthreads();

    if (v < MAXN - 1){
      // ============ phase B: GEMM2 (Wg/Wm own 16 cols) + gated + gather ============
      {
        f32x4 acc[2][2];
        #pragma unroll
        for (int rr = 0; rr < 2; ++rr)
          #pragma unroll
          for (int s = 0; s < 2; ++s) acc[rr][s] = (f32x4){0.f,0.f,0.f,0.f};

        const ushort* Ab = g_Hv + (size_t)(rb + rf0*16 + lr)*KP + lk*8;
        #pragma unroll 4
        for (int ks = 0; ks < 16; ++ks){
          s16x8 a0 = *(const s16x8*)(Ab + ks*32);
          s16x8 a1 = *(const s16x8*)(Ab + 16*KP + ks*32);
          s16x8 b0 = *(const s16x8*)((const char*)sW2 + (0*16 + lr)*1024
                      + ((ks*64 + lk*16) ^ ((lr & 7) << 4)));
          s16x8 b1 = *(const s16x8*)((const char*)sW2 + (16 + lr)*1024
                      + ((ks*64 + lk*16) ^ (((16 + lr) & 7) << 4)));
          acc[0][0] = __builtin_amdgcn_mfma_f32_16x16x32_bf16(a0, b0, acc[0][0], 0, 0, 0);
          acc[0][1] = __builtin_amdgcn_mfma_f32_16x16x32_bf16(a0, b1, acc[0][1], 0, 0, 0);
          acc[1][0] = __builtin_amdgcn_mfma_f32_16x16x32_bf16(a1, b0, acc[1][0], 0, 0, 0);
          acc[1][1] = __builtin_amdgcn_mfma_f32_16x16x32_bf16(a1, b1, acc[1][1], 0, 0, 0);
        }

        const int h = c0 + lr;
        const float bgh = g_bgt[h] + g_wgid[v*KP + h];
        const float bmh = g_wmid[v*KP + h];
        #pragma unroll
        for (int rr = 0; rr < 2; ++rr){
          #pragma unroll
          for (int r = 0; r < 4; ++r){
            const int lrow = (rf0 + rr)*16 + lk*4 + r;
            const int row = rb + lrow;
            const float sg = sigm(acc[rr][0][r] + bgh);
            const float mg = acc[rr][1][r] + bmh;
            float gv = sg * mg;
            if (h >= HS) gv = 0.f;
            const ushort gvb = f2b(gv);
            g_gated[((size_t)row*MAXN + v)*KP + h] = gvb;
            sGt[lrow*16 + lr] = gvb;
          }
        }
      }
      __syncthreads();

      {
        // gather next Hin: 512 threads = 256 rows x 2 col-halves (8 cols, 16B)
        const int l    = tid >> 1;
        const int half = tid & 1;
        const int row  = rb + l;
        const int hb   = c0 + half*8;
        unsigned m = g_adjm[row*MAXN + v + 1];
        float a8[8] = {0.f,0.f,0.f,0.f,0.f,0.f,0.f,0.f};
        while (m){
          const int n = __builtin_ctz(m); m &= m - 1;
          s16x8 x;
          if (n == v) x = *(const s16x8*)(sGt + l*16 + half*8);
          else        x = *(const s16x8*)(g_gated + ((size_t)row*MAXN + n)*KP + hb);
          #pragma unroll
          for (int j = 0; j < 8; ++j) a8[j] += b2f((ushort)x[j]);
        }
        s16x8 o;
        #pragma unroll
        for (int j = 0; j < 8; ++j) o[j] = (short)f2b(a8[j]);
        *(s16x8*)(g_Hin + (size_t)row*KP + hb) = o;
      }
      // ---- group barrier: Hin complete for the stripe ----
      __syncthreads();
      ++ep;
      if (tid == 0){
        __hip_atomic_fetch_add(&g_barp[grp].c, 1u, __ATOMIC_RELEASE, __HIP_MEMORY_SCOPE_AGENT);
        const unsigned tgt = ep*32u;
        while (__hip_atomic_load(&g_barp[grp].c, __ATOMIC_ACQUIRE, __HIP_MEMORY_SCOPE_AGENT) < tgt)
          __builtin_amdgcn_s_sleep(1);
      }
      __syncthreads();
    } else {
      // ============ final: mu/logvar = Hv(31) @ [W1;W2]^T + b ============
      if (w < 4){
        const int rf = J & 15;       // row-fragment of this group's stripe
        const int cf = (J >> 4)*4 + w;
        if (cf < 7){
          const ushort* Ab = g_Hv + (size_t)(rb + rf*16 + lr)*KP + lk*8;
          const ushort* Bb = g_Wf + (size_t)(cf*16 + lr)*KP + lk*8;
          f32x4 acc = (f32x4){0.f,0.f,0.f,0.f};
          #pragma unroll 4
          for (int ks = 0; ks < 16; ++ks){
            s16x8 a0 = *(const s16x8*)(Ab + ks*32);
            s16x8 b0 = *(const s16x8*)(Bb + ks*32);
            acc = __builtin_amdgcn_mfma_f32_16x16x32_bf16(a0, b0, acc, 0, 0, 0);
          }
          const int j2 = cf*16 + lr;
          #pragma unroll
          for (int r = 0; r < 4; ++r){
            const int row = rb + rf*16 + lk*4 + r;
            const float val = acc[r] + g_bias[j2];
            if (j2 < 56)       out[(size_t)row*56 + j2] = val;
            else if (j2 < 112) out[(size_t)NB*56 + (size_t)row*56 + (j2 - 56)] = val;
          }
        }
      }
    }
  }
}

extern "C" void kernel_launch(void* const* d_in, const int* in_sizes, int n_in,
                              void* d_out, int out_size, void* d_ws, size_t ws_size,
                              hipStream_t stream){
  const int*   node_types = (const int*)d_in[0];
  const void*  adj        = (const void*)d_in[1];
  const float* W_ih       = (const float*)d_in[2];
  const float* W_hh       = (const float*)d_in[3];
  const float* b_ih       = (const float*)d_in[4];
  const float* b_hh       = (const float*)d_in[5];
  const float* Wg         = (const float*)d_in[6];
  const float* bg         = (const float*)d_in[7];
  const float* Wm         = (const float*)d_in[8];
  const float* W1         = (const float*)d_in[9];
  const float* b1         = (const float*)d_in[10];
  const float* W2         = (const float*)d_in[11];
  const float* b2         = (const float*)d_in[12];
  float* out = (float*)d_out;

  const int NPREP1 = 3*KP*KP + 2*KP*KP + 128*KP;
  const int NPREP2 = NVT*3*KP + 3*KP + 2*MAXN*KP + KP + 128 + NB*MAXN;

  detect_adj  <<<1, 256, 0, stream>>>(adj);
  prep_weights<<<(NPREP1 + 255)/256, 256, 0, stream>>>(W_hh, Wg, Wm, W1, W2);
  prep_tables <<<(NPREP2 + 255)/256, 256, 0, stream>>>(W_ih, b_ih, b_hh, Wg, Wm, bg, b1, b2, adj);

  void* kargs[] = { (void*)&node_types, (void*)&out };
  hipLaunchCooperativeKernel((void*)k_steps, dim3(256), dim3(512), kargs, 0, stream);
}

// Round 10
// 1483.258 us; speedup vs baseline: 2.8123x; 1.0352x over previous
//
#include <hip/hip_runtime.h>

#define HS 501
#define VS 533
#define KP 512
#define NB 2048
#define MAXN 32
#define NVT 10

typedef short s16x8 __attribute__((ext_vector_type(8)));
typedef float f32x4 __attribute__((ext_vector_type(4)));

// ---- static device buffers (rewritten every launch before being read) ----
__device__ ushort  g_Wb1[3*KP*KP];      // [gate][h][k] bf16, zero-padded (planar 1536x512)
__device__ ushort  g_Wb2[2*KP*KP];      // [s][h][k]   (s=0:Wg, s=1:Wm)  (planar 1024x512)
__device__ ushort  g_Wf [128*KP];       // [j][k] rows 0..55=W1, 56..111=W2
__device__ float   g_giT[NVT*3*KP];     // [t][gate][h] = W_ih col t + b_ih
__device__ float   g_bhh[3*KP];
__device__ float   g_wgid[MAXN*KP];     // Wg[:,501+v]
__device__ float   g_wmid[MAXN*KP];     // Wm[:,501+v]
__device__ float   g_bgt[KP];
__device__ float   g_bias[128];
__device__ unsigned g_adjm[NB*MAXN];    // bit n = adj[b,n,v]
__device__ ushort  g_Hin[NB*KP];        // gathered GRU input H (bf16)
__device__ ushort  g_Hv [NB*KP];        // GRU output of current step (bf16)
__device__ ushort  g_gated[NB*MAXN*KP]; // cached gated rows (bf16)
__device__ int     g_adjfmt;            // 0=int32, 1=float32, 2=byte

// per-block arrival flags: one cacheline each, grouped by barrier-group.
// Arrival = release-store of monotone epoch; no RMW -> no serialization.
struct alignas(128) Flag { unsigned v; unsigned pad[31]; };
__device__ Flag g_flags[8][32];

__device__ __forceinline__ float b2f(ushort h){ return __uint_as_float(((unsigned)h)<<16); }
__device__ __forceinline__ ushort f2b(float f){
  unsigned u = __float_as_uint(f);
  u += 0x7FFFu + ((u>>16)&1u);
  return (ushort)(u>>16);
}
__device__ __forceinline__ float sigm(float x){ return 1.f/(1.f + __expf(-x)); }
__device__ __forceinline__ float tanh_f(float x){ return 1.f - 2.f/(1.f + __expf(2.f*x)); }

// ---------------- adj dtype detector + flag reset ----------------
__global__ __launch_bounds__(256) void detect_adj(const void* __restrict__ adj){
  __shared__ int bad_i32, bad_f32;
  if (threadIdx.x == 0){ bad_i32 = 0; bad_f32 = 0; }
  ((Flag*)g_flags)[threadIdx.x].v = 0u;   // 256 threads cover all 8x32 flags
  __syncthreads();
  const int*   ai = (const int*)adj;
  const float* af = (const float*)adj;
  int li = 0, lf = 0;
  for (int i = threadIdx.x; i < 1024; i += 256){
    int w = ai[i];
    if (w != 0 && w != 1) li = 1;
    float f = af[i];
    if (f != 0.f && f != 1.f) lf = 1;
  }
  if (li) atomicOr(&bad_i32, 1);
  if (lf) atomicOr(&bad_f32, 1);
  __syncthreads();
  if (threadIdx.x == 0)
    g_adjfmt = (!bad_i32) ? 0 : (!bad_f32) ? 1 : 2;
}

// ---------------- setup kernels ----------------
__global__ __launch_bounds__(256) void prep_weights(const float* __restrict__ W_hh,
                                                    const float* __restrict__ Wg,
                                                    const float* __restrict__ Wm,
                                                    const float* __restrict__ W1,
                                                    const float* __restrict__ W2){
  int i = blockIdx.x*256 + threadIdx.x;
  const int NW1 = 3*KP*KP, NW2 = 2*KP*KP, NWF = 128*KP;
  if (i < NW1){
    int g = i >> 18; int rem = i & 0x3FFFF; int h = rem >> 9; int k = rem & 511;
    float v = (h < HS && k < HS) ? W_hh[(g*HS + h)*HS + k] : 0.f;
    g_Wb1[i] = f2b(v);
  } else if (i < NW1 + NW2){
    int j = i - NW1; int s = j >> 18; int rem = j & 0x3FFFF; int h = rem >> 9; int k = rem & 511;
    const float* src = s ? Wm : Wg;
    float v = (h < HS && k < HS) ? src[h*VS + k] : 0.f;
    g_Wb2[j] = f2b(v);
  } else if (i < NW1 + NW2 + NWF){
    int j = i - NW1 - NW2; int r = j >> 9; int k = j & 511;
    float v = 0.f;
    if (k < HS){
      if (r < 56) v = W1[r*HS + k];
      else if (r < 112) v = W2[(r-56)*HS + k];
    }
    g_Wf[j] = f2b(v);
  }
}

__global__ __launch_bounds__(256) void prep_tables(const float* __restrict__ W_ih,
                                                   const float* __restrict__ b_ih,
                                                   const float* __restrict__ b_hh,
                                                   const float* __restrict__ Wg,
                                                   const float* __restrict__ Wm,
                                                   const float* __restrict__ bg,
                                                   const float* __restrict__ b1,
                                                   const float* __restrict__ b2,
                                                   const void* __restrict__ adj){
  int i = blockIdx.x*256 + threadIdx.x;
  if (i < NVT*3*KP){
    int t = i / 1536; int rem = i - t*1536; int g = rem >> 9; int h = rem & 511;
    g_giT[i] = (h < HS) ? W_ih[(g*HS + h)*NVT + t] + b_ih[g*HS + h] : 0.f;
    return;
  }
  i -= NVT*3*KP;
  if (i < 3*KP){
    int g = i >> 9, h = i & 511;
    g_bhh[i] = (h < HS) ? b_hh[g*HS + h] : 0.f;
    return;
  }
  i -= 3*KP;
  if (i < MAXN*KP){
    int v = i >> 9, h = i & 511;
    g_wgid[i] = (h < HS) ? Wg[h*VS + HS + v] : 0.f;
    return;
  }
  i -= MAXN*KP;
  if (i < MAXN*KP){
    int v = i >> 9, h = i & 511;
    g_wmid[i] = (h < HS) ? Wm[h*VS + HS + v] : 0.f;
    return;
  }
  i -= MAXN*KP;
  if (i < KP){ g_bgt[i] = (i < HS) ? bg[i] : 0.f; return; }
  i -= KP;
  if (i < 128){ g_bias[i] = (i < 56) ? b1[i] : (i < 112) ? b2[i-56] : 0.f; return; }
  i -= 128;
  if (i < NB*MAXN){
    int b = i >> 5, v = i & 31;
    const int fmt = g_adjfmt;
    unsigned m = 0;
    const size_t base = (size_t)b*MAXN*MAXN + v;
    if (fmt == 0){
      const int* a = (const int*)adj;
      for (int n = 0; n < MAXN; ++n) if (a[base + (size_t)n*MAXN] != 0) m |= (1u << n);
    } else if (fmt == 1){
      const float* a = (const float*)adj;
      for (int n = 0; n < MAXN; ++n) if (a[base + (size_t)n*MAXN] != 0.f) m |= (1u << n);
    } else {
      const unsigned char* a = (const unsigned char*)adj;
      for (int n = 0; n < MAXN; ++n) if (a[base + (size_t)n*MAXN]) m |= (1u << n);
    }
    g_adjm[i] = m;
  }
}

// flag-array group barrier: parallel release-store arrivals + wave-0 parallel poll.
#define GROUP_BARRIER()                                                                 \
  do {                                                                                  \
    __syncthreads();                                                                    \
    ++ep;                                                                               \
    if (tid == 0)                                                                       \
      __hip_atomic_store(&g_flags[grp][J].v, ep, __ATOMIC_RELEASE,                      \
                         __HIP_MEMORY_SCOPE_AGENT);                                     \
    if (w == 0){                                                                        \
      for (;;){                                                                         \
        unsigned x = __hip_atomic_load(&g_flags[grp][lane & 31].v, __ATOMIC_RELAXED,    \
                                       __HIP_MEMORY_SCOPE_AGENT);                       \
        if (__all((int)(x >= ep))) break;                                               \
        __builtin_amdgcn_s_sleep(1);                                                    \
      }                                                                                 \
      __threadfence();                                                                  \
    }                                                                                   \
    __syncthreads();                                                                    \
  } while (0)

// =============== cooperative kernel, XCD-local layout, flag barriers ===============
// 256 blocks x 512 threads (1/CU, co-resident via cooperative launch). Group
// grp=blockIdx&7 owns rows [grp*256,+256); groups share NO data, so sync is
// per-group (32 blocks) with agent-scope release/acquire — correct regardless
// of block->XCD placement, fast when placement round-robins. Col-slice
// J=blockIdx>>3 owns h-cols [J*16,+16) across all gates/planes -> every
// epilogue is block-local. W_hh + Wg/Wm slices live in LDS.
__global__ __launch_bounds__(512) void k_steps(const int* __restrict__ node_types,
                                               float* __restrict__ out){
  __shared__ ushort sW1[48*512];   // 48 KB: [gate*16+col][k], XOR-swizzled
  __shared__ ushort sW2[32*512];   // 32 KB: [plane*16+col][k], XOR-swizzled
  __shared__ ushort sGt[256*16];   // 8 KB: current-step gated (stripe x own cols)

  const int tid  = threadIdx.x;
  const int lane = tid & 63;
  const int w    = tid >> 6;        // wave 0..7
  const int lr   = lane & 15;
  const int lk   = lane >> 4;
  const int grp  = blockIdx.x & 7;
  const int J    = blockIdx.x >> 3; // 0..31
  const int c0   = J*16;
  const int rb   = grp*256;
  const int rf0  = w*2;             // this wave's two row-fragments

  // ---- prologue: stage W_hh slice (48 rows) + Wg/Wm slice (32 rows) into LDS ----
  for (int idx = tid; idx < 80*64; idx += 512){
    const int r = idx >> 6, c = idx & 63;
    if (r < 48){
      const int gt = r >> 4, col = r & 15;
      s16x8 x = *(const s16x8*)(g_Wb1 + (size_t)(gt*KP + c0 + col)*KP + c*8);
      *(s16x8*)((char*)sW1 + r*1024 + ((c*16) ^ ((r & 7) << 4))) = x;
    } else {
      const int r2 = r - 48;
      const int pl = r2 >> 4, col = r2 & 15;
      s16x8 x = *(const s16x8*)(g_Wb2 + (size_t)(pl*KP + c0 + col)*KP + c*8);
      *(s16x8*)((char*)sW2 + r2*1024 + ((c*16) ^ ((r2 & 7) << 4))) = x;
    }
  }
  __syncthreads();

  unsigned ep = 0;  // barrier epoch (uniform across block)

  for (int v = 0; v < MAXN; ++v){
    // ================= phase A: GEMM1 (3 gates, own 16 cols) + GRU =================
    {
      f32x4 acc[2][3];
      #pragma unroll
      for (int rr = 0; rr < 2; ++rr)
        #pragma unroll
        for (int g = 0; g < 3; ++g) acc[rr][g] = (f32x4){0.f,0.f,0.f,0.f};

      if (v > 0){
        const ushort* Ab = g_Hin + (size_t)(rb + rf0*16 + lr)*KP + lk*8;
        #pragma unroll 4
        for (int ks = 0; ks < 16; ++ks){
          s16x8 a0 = *(const s16x8*)(Ab + ks*32);
          s16x8 a1 = *(const s16x8*)(Ab + 16*KP + ks*32);
          #pragma unroll
          for (int g = 0; g < 3; ++g){
            s16x8 bf = *(const s16x8*)((const char*)sW1 + (g*16 + lr)*1024
                        + ((ks*64 + lk*16) ^ ((lr & 7) << 4)));
            acc[0][g] = __builtin_amdgcn_mfma_f32_16x16x32_bf16(a0, bf, acc[0][g], 0, 0, 0);
            acc[1][g] = __builtin_amdgcn_mfma_f32_16x16x32_bf16(a1, bf, acc[1][g], 0, 0, 0);
          }
        }
      }

      const int h = c0 + lr;
      const float gbr = g_bhh[0*KP + h];
      const float gbz = g_bhh[1*KP + h];
      const float gbn = g_bhh[2*KP + h];
      #pragma unroll
      for (int rr = 0; rr < 2; ++rr){
        #pragma unroll
        for (int r = 0; r < 4; ++r){
          const int row = rb + (rf0 + rr)*16 + lk*4 + r;
          const int t = node_types[row*MAXN + v];
          const float gir = g_giT[(t*3 + 0)*KP + h];
          const float giz = g_giT[(t*3 + 1)*KP + h];
          const float gin = g_giT[(t*3 + 2)*KP + h];
          const float rg = sigm(gir + acc[rr][0][r] + gbr);
          const float zg = sigm(giz + acc[rr][1][r] + gbz);
          const float ng = tanh_f(gin + rg*(acc[rr][2][r] + gbn));
          const float hp = (v > 0) ? b2f(g_Hin[(size_t)row*KP + h]) : 0.f;
          const float hv = (1.f - zg)*ng + zg*hp;
          g_Hv[(size_t)row*KP + h] = (h < HS) ? f2b(hv) : (ushort)0;
        }
      }
    }
    GROUP_BARRIER();   // Hv complete for the stripe

    if (v < MAXN - 1){
      // ============ phase B: GEMM2 (Wg/Wm own 16 cols) + gated + gather ============
      {
        f32x4 acc[2][2];
        #pragma unroll
        for (int rr = 0; rr < 2; ++rr)
          #pragma unroll
          for (int s = 0; s < 2; ++s) acc[rr][s] = (f32x4){0.f,0.f,0.f,0.f};

        const ushort* Ab = g_Hv + (size_t)(rb + rf0*16 + lr)*KP + lk*8;
        #pragma unroll 4
        for (int ks = 0; ks < 16; ++ks){
          s16x8 a0 = *(const s16x8*)(Ab + ks*32);
          s16x8 a1 = *(const s16x8*)(Ab + 16*KP + ks*32);
          s16x8 b0 = *(const s16x8*)((const char*)sW2 + (0*16 + lr)*1024
                      + ((ks*64 + lk*16) ^ ((lr & 7) << 4)));
          s16x8 b1 = *(const s16x8*)((const char*)sW2 + (16 + lr)*1024
                      + ((ks*64 + lk*16) ^ (((16 + lr) & 7) << 4)));
          acc[0][0] = __builtin_amdgcn_mfma_f32_16x16x32_bf16(a0, b0, acc[0][0], 0, 0, 0);
          acc[0][1] = __builtin_amdgcn_mfma_f32_16x16x32_bf16(a0, b1, acc[0][1], 0, 0, 0);
          acc[1][0] = __builtin_amdgcn_mfma_f32_16x16x32_bf16(a1, b0, acc[1][0], 0, 0, 0);
          acc[1][1] = __builtin_amdgcn_mfma_f32_16x16x32_bf16(a1, b1, acc[1][1], 0, 0, 0);
        }

        const int h = c0 + lr;
        const float bgh = g_bgt[h] + g_wgid[v*KP + h];
        const float bmh = g_wmid[v*KP + h];
        #pragma unroll
        for (int rr = 0; rr < 2; ++rr){
          #pragma unroll
          for (int r = 0; r < 4; ++r){
            const int lrow = (rf0 + rr)*16 + lk*4 + r;
            const int row = rb + lrow;
            const float sg = sigm(acc[rr][0][r] + bgh);
            const float mg = acc[rr][1][r] + bmh;
            float gv = sg * mg;
            if (h >= HS) gv = 0.f;
            const ushort gvb = f2b(gv);
            g_gated[((size_t)row*MAXN + v)*KP + h] = gvb;
            sGt[lrow*16 + lr] = gvb;
          }
        }
      }
      __syncthreads();

      {
        // gather next Hin: 512 threads = 256 rows x 2 col-halves (8 cols, 16B)
        const int l    = tid >> 1;
        const int half = tid & 1;
        const int row  = rb + l;
        const int hb   = c0 + half*8;
        unsigned m = g_adjm[row*MAXN + v + 1];
        float a8[8] = {0.f,0.f,0.f,0.f,0.f,0.f,0.f,0.f};
        while (m){
          const int n = __builtin_ctz(m); m &= m - 1;
          s16x8 x;
          if (n == v) x = *(const s16x8*)(sGt + l*16 + half*8);
          else        x = *(const s16x8*)(g_gated + ((size_t)row*MAXN + n)*KP + hb);
          #pragma unroll
          for (int j = 0; j < 8; ++j) a8[j] += b2f((ushort)x[j]);
        }
        s16x8 o;
        #pragma unroll
        for (int j = 0; j < 8; ++j) o[j] = (short)f2b(a8[j]);
        *(s16x8*)(g_Hin + (size_t)row*KP + hb) = o;
      }
      GROUP_BARRIER();   // Hin complete for the stripe
    } else {
      // ============ final: mu/logvar = Hv(31) @ [W1;W2]^T + b ============
      if (w < 4){
        const int rf = J & 15;       // row-fragment of this group's stripe
        const int cf = (J >> 4)*4 + w;
        if (cf < 7){
          const ushort* Ab = g_Hv + (size_t)(rb + rf*16 + lr)*KP + lk*8;
          const ushort* Bb = g_Wf + (size_t)(cf*16 + lr)*KP + lk*8;
          f32x4 acc = (f32x4){0.f,0.f,0.f,0.f};
          #pragma unroll 4
          for (int ks = 0; ks < 16; ++ks){
            s16x8 a0 = *(const s16x8*)(Ab + ks*32);
            s16x8 b0 = *(const s16x8*)(Bb + ks*32);
            acc = __builtin_amdgcn_mfma_f32_16x16x32_bf16(a0, b0, acc, 0, 0, 0);
          }
          const int j2 = cf*16 + lr;
          #pragma unroll
          for (int r = 0; r < 4; ++r){
            const int row = rb + rf*16 + lk*4 + r;
            const float val = acc[r] + g_bias[j2];
            if (j2 < 56)       out[(size_t)row*56 + j2] = val;
            else if (j2 < 112) out[(size_t)NB*56 + (size_t)row*56 + (j2 - 56)] = val;
          }
        }
      }
    }
  }
}

extern "C" void kernel_launch(void* const* d_in, const int* in_sizes, int n_in,
                              void* d_out, int out_size, void* d_ws, size_t ws_size,
                              hipStream_t stream){
  const int*   node_types = (const int*)d_in[0];
  const void*  adj        = (const void*)d_in[1];
  const float* W_ih       = (const float*)d_in[2];
  const float* W_hh       = (const float*)d_in[3];
  const float* b_ih       = (const float*)d_in[4];
  const float* b_hh       = (const float*)d_in[5];
  const float* Wg         = (const float*)d_in[6];
  const float* bg         = (const float*)d_in[7];
  const float* Wm         = (const float*)d_in[8];
  const float* W1         = (const float*)d_in[9];
  const float* b1         = (const float*)d_in[10];
  const float* W2         = (const float*)d_in[11];
  const float* b2         = (const float*)d_in[12];
  float* out = (float*)d_out;

  const int NPREP1 = 3*KP*KP + 2*KP*KP + 128*KP;
  const int NPREP2 = NVT*3*KP + 3*KP + 2*MAXN*KP + KP + 128 + NB*MAXN;

  detect_adj  <<<1, 256, 0, stream>>>(adj);
  prep_weights<<<(NPREP1 + 255)/256, 256, 0, stream>>>(W_hh, Wg, Wm, W1, W2);
  prep_tables <<<(NPREP2 + 255)/256, 256, 0, stream>>>(W_ih, b_ih, b_hh, Wg, Wm, bg, b1, b2, adj);

  void* kargs[] = { (void*)&node_types, (void*)&out };
  hipLaunchCooperativeKernel((void*)k_steps, dim3(256), dim3(512), kargs, 0, stream);
}

// Round 12
// 927.928 us; speedup vs baseline: 4.4953x; 1.5985x over previous
//
#include <hip/hip_runtime.h>

#define HS 501
#define VS 533
#define KP 512
#define NB 2048
#define MAXN 32
#define NVT 10

typedef short s16x8 __attribute__((ext_vector_type(8)));
typedef float f32x4 __attribute__((ext_vector_type(4)));

// ---- static device buffers (rewritten every launch before being read) ----
__device__ ushort  g_Wb1[3*KP*KP];      // [gate][h][k] bf16, zero-padded (planar 1536x512)
__device__ ushort  g_Wb2[2*KP*KP];      // [s][h][k]   (s=0:Wg, s=1:Wm)  (planar 1024x512)
__device__ ushort  g_Wf [128*KP];       // [j][k] rows 0..55=W1, 56..111=W2
__device__ float   g_giT[NVT*3*KP];     // [t][gate][h] = W_ih col t + b_ih
__device__ float   g_bhh[3*KP];
__device__ float   g_wgid[MAXN*KP];     // Wg[:,501+v]
__device__ float   g_wmid[MAXN*KP];     // Wm[:,501+v]
__device__ float   g_bgt[KP];
__device__ float   g_bias[128];
__device__ unsigned g_adjm[NB*MAXN];    // bit n = adj[b,n,v]
__device__ ushort  g_Hin[NB*KP];        // gathered GRU input H (bf16)
__device__ ushort  g_Hv [NB*KP];        // GRU output of current step (bf16)
__device__ ushort  g_gated[NB*MAXN*KP]; // cached gated rows (bf16)
__device__ int     g_adjfmt;            // 0=int32, 1=float32, 2=byte
__device__ unsigned g_xcc[8][32];       // per-block hardware XCC id

// per-block arrival flags: one cacheline each, grouped by barrier-group.
struct alignas(128) Flag { unsigned v; unsigned pad[31]; };
__device__ Flag g_flags[8][32];

__device__ __forceinline__ float b2f(ushort h){ return __uint_as_float(((unsigned)h)<<16); }
__device__ __forceinline__ ushort f2b(float f){
  unsigned u = __float_as_uint(f);
  u += 0x7FFFu + ((u>>16)&1u);
  return (ushort)(u>>16);
}
__device__ __forceinline__ float sigm(float x){ return 1.f/(1.f + __expf(-x)); }
__device__ __forceinline__ float tanh_f(float x){ return 1.f - 2.f/(1.f + __expf(2.f*x)); }

// ---------------- adj dtype detector + flag reset ----------------
__global__ __launch_bounds__(256) void detect_adj(const void* __restrict__ adj){
  __shared__ int bad_i32, bad_f32;
  if (threadIdx.x == 0){ bad_i32 = 0; bad_f32 = 0; }
  ((Flag*)g_flags)[threadIdx.x].v = 0u;   // 256 threads cover all 8x32 flags
  __syncthreads();
  const int*   ai = (const int*)adj;
  const float* af = (const float*)adj;
  int li = 0, lf = 0;
  for (int i = threadIdx.x; i < 1024; i += 256){
    int w = ai[i];
    if (w != 0 && w != 1) li = 1;
    float f = af[i];
    if (f != 0.f && f != 1.f) lf = 1;
  }
  if (li) atomicOr(&bad_i32, 1);
  if (lf) atomicOr(&bad_f32, 1);
  __syncthreads();
  if (threadIdx.x == 0)
    g_adjfmt = (!bad_i32) ? 0 : (!bad_f32) ? 1 : 2;
}

// ---------------- setup kernels ----------------
__global__ __launch_bounds__(256) void prep_weights(const float* __restrict__ W_hh,
                                                    const float* __restrict__ Wg,
                                                    const float* __restrict__ Wm,
                                                    const float* __restrict__ W1,
                                                    const float* __restrict__ W2){
  int i = blockIdx.x*256 + threadIdx.x;
  const int NW1 = 3*KP*KP, NW2 = 2*KP*KP, NWF = 128*KP;
  if (i < NW1){
    int g = i >> 18; int rem = i & 0x3FFFF; int h = rem >> 9; int k = rem & 511;
    float v = (h < HS && k < HS) ? W_hh[(g*HS + h)*HS + k] : 0.f;
    g_Wb1[i] = f2b(v);
  } else if (i < NW1 + NW2){
    int j = i - NW1; int s = j >> 18; int rem = j & 0x3FFFF; int h = rem >> 9; int k = rem & 511;
    const float* src = s ? Wm : Wg;
    float v = (h < HS && k < HS) ? src[h*VS + k] : 0.f;
    g_Wb2[j] = f2b(v);
  } else if (i < NW1 + NW2 + NWF){
    int j = i - NW1 - NW2; int r = j >> 9; int k = j & 511;
    float v = 0.f;
    if (k < HS){
      if (r < 56) v = W1[r*HS + k];
      else if (r < 112) v = W2[(r-56)*HS + k];
    }
    g_Wf[j] = f2b(v);
  }
}

__global__ __launch_bounds__(256) void prep_tables(const float* __restrict__ W_ih,
                                                   const float* __restrict__ b_ih,
                                                   const float* __restrict__ b_hh,
                                                   const float* __restrict__ Wg,
                                                   const float* __restrict__ Wm,
                                                   const float* __restrict__ bg,
                                                   const float* __restrict__ b1,
                                                   const float* __restrict__ b2,
                                                   const void* __restrict__ adj){
  int i = blockIdx.x*256 + threadIdx.x;
  if (i < NVT*3*KP){
    int t = i / 1536; int rem = i - t*1536; int g = rem >> 9; int h = rem & 511;
    g_giT[i] = (h < HS) ? W_ih[(g*HS + h)*NVT + t] + b_ih[g*HS + h] : 0.f;
    return;
  }
  i -= NVT*3*KP;
  if (i < 3*KP){
    int g = i >> 9, h = i & 511;
    g_bhh[i] = (h < HS) ? b_hh[g*HS + h] : 0.f;
    return;
  }
  i -= 3*KP;
  if (i < MAXN*KP){
    int v = i >> 9, h = i & 511;
    g_wgid[i] = (h < HS) ? Wg[h*VS + HS + v] : 0.f;
    return;
  }
  i -= MAXN*KP;
  if (i < MAXN*KP){
    int v = i >> 9, h = i & 511;
    g_wmid[i] = (h < HS) ? Wm[h*VS + HS + v] : 0.f;
    return;
  }
  i -= MAXN*KP;
  if (i < KP){ g_bgt[i] = (i < HS) ? bg[i] : 0.f; return; }
  i -= KP;
  if (i < 128){ g_bias[i] = (i < 56) ? b1[i] : (i < 112) ? b2[i-56] : 0.f; return; }
  i -= 128;
  if (i < NB*MAXN){
    int b = i >> 5, v = i & 31;
    const int fmt = g_adjfmt;
    unsigned m = 0;
    const size_t base = (size_t)b*MAXN*MAXN + v;
    if (fmt == 0){
      const int* a = (const int*)adj;
      for (int n = 0; n < MAXN; ++n) if (a[base + (size_t)n*MAXN] != 0) m |= (1u << n);
    } else if (fmt == 1){
      const float* a = (const float*)adj;
      for (int n = 0; n < MAXN; ++n) if (a[base + (size_t)n*MAXN] != 0.f) m |= (1u << n);
    } else {
      const unsigned char* a = (const unsigned char*)adj;
      for (int n = 0; n < MAXN; ++n) if (a[base + (size_t)n*MAXN]) m |= (1u << n);
    }
    g_adjm[i] = m;
  }
}

// Group barrier, two modes:
//  pure (group verified on one XCD): syncthreads drains stores to the shared L2;
//    relaxed flag store + L1-bypassing poll; then vector-L1 invalidate only.
//    L2 stays warm — no wbl2/inv sc1.
//  impure fallback: full agent-scope release/acquire (round-10 proven path).
#define GROUP_BARRIER()                                                                 \
  do {                                                                                  \
    __syncthreads();                                                                    \
    ++ep;                                                                               \
    if (pure){                                                                          \
      if (tid == 0)                                                                     \
        __hip_atomic_store(&g_flags[grp][J].v, ep, __ATOMIC_RELAXED,                    \
                           __HIP_MEMORY_SCOPE_AGENT);                                   \
      if (w == 0){                                                                      \
        for (;;){                                                                       \
          unsigned x = __hip_atomic_load(&g_flags[grp][lane & 31].v, __ATOMIC_RELAXED,  \
                                         __HIP_MEMORY_SCOPE_AGENT);                     \
          if (__all((int)(x >= ep))) break;                                             \
          __builtin_amdgcn_s_sleep(1);                                                  \
        }                                                                               \
        asm volatile("buffer_inv\n\ts_waitcnt vmcnt(0)" ::: "memory");                  \
      }                                                                                 \
    } else {                                                                            \
      if (tid == 0)                                                                     \
        __hip_atomic_store(&g_flags[grp][J].v, ep, __ATOMIC_RELEASE,                    \
                           __HIP_MEMORY_SCOPE_AGENT);                                   \
      if (w == 0){                                                                      \
        for (;;){                                                                       \
          unsigned x = __hip_atomic_load(&g_flags[grp][lane & 31].v, __ATOMIC_RELAXED,  \
                                         __HIP_MEMORY_SCOPE_AGENT);                     \
          if (__all((int)(x >= ep))) break;                                             \
          __builtin_amdgcn_s_sleep(1);                                                  \
        }                                                                               \
        __threadfence();                                                                \
      }                                                                                 \
    }                                                                                   \
    __syncthreads();                                                                    \
  } while (0)

// =============== cooperative kernel, XCD-local layout, scoped barriers ===============
__global__ __launch_bounds__(512) void k_steps(const int* __restrict__ node_types,
                                               float* __restrict__ out){
  __shared__ ushort sW1[48*512];   // 48 KB: [gate*16+col][k], XOR-swizzled
  __shared__ ushort sW2[32*512];   // 32 KB: [plane*16+col][k], XOR-swizzled
  __shared__ ushort sGt[256*16];   // 8 KB: current-step gated (stripe x own cols)
  __shared__ int    sPure;

  const int tid  = threadIdx.x;
  const int lane = tid & 63;
  const int w    = tid >> 6;        // wave 0..7
  const int lr   = lane & 15;
  const int lk   = lane >> 4;
  const int grp  = blockIdx.x & 7;
  const int J    = blockIdx.x >> 3; // 0..31
  const int c0   = J*16;
  const int rb   = grp*256;
  const int rf0  = w*2;             // this wave's two row-fragments

  // ---- prologue: stage W_hh slice (48 rows) + Wg/Wm slice (32 rows) into LDS ----
  for (int idx = tid; idx < 80*64; idx += 512){
    const int r = idx >> 6, c = idx & 63;
    if (r < 48){
      const int gt = r >> 4, col = r & 15;
      s16x8 x = *(const s16x8*)(g_Wb1 + (size_t)(gt*KP + c0 + col)*KP + c*8);
      *(s16x8*)((char*)sW1 + r*1024 + ((c*16) ^ ((r & 7) << 4))) = x;
    } else {
      const int r2 = r - 48;
      const int pl = r2 >> 4, col = r2 & 15;
      s16x8 x = *(const s16x8*)(g_Wb2 + (size_t)(pl*KP + c0 + col)*KP + c*8);
      *(s16x8*)((char*)sW2 + r2*1024 + ((c*16) ^ ((r2 & 7) << 4))) = x;
    }
  }

  // ---- publish hardware XCC id, then one heavy (agent-scope) group barrier ----
  if (tid == 0){
    unsigned xcc;
    asm volatile("s_getreg_b32 %0, hwreg(HW_REG_XCC_ID)" : "=s"(xcc));
    g_xcc[grp][J] = xcc;
  }
  unsigned ep = 0;
  {
    const bool pure = false;  // heavy path for the prologue barrier
    GROUP_BARRIER();
  }
  // ---- purity check: group entirely on one XCD? (uniform across the group) ----
  if (w == 0){
    const unsigned mine = g_xcc[grp][lane & 31];
    const unsigned ref  = g_xcc[grp][0];
    const int ok = __all((int)(mine == ref));
    if (lane == 0) sPure = ok;
  }
  __syncthreads();
  const bool pure = (sPure != 0);

  for (int v = 0; v < MAXN; ++v){
    // ================= phase A: GEMM1 (3 gates, own 16 cols) + GRU =================
    {
      f32x4 acc[2][3];
      #pragma unroll
      for (int rr = 0; rr < 2; ++rr)
        #pragma unroll
        for (int g = 0; g < 3; ++g) acc[rr][g] = (f32x4){0.f,0.f,0.f,0.f};

      if (v > 0){
        const ushort* Ab = g_Hin + (size_t)(rb + rf0*16 + lr)*KP + lk*8;
        #pragma unroll 4
        for (int ks = 0; ks < 16; ++ks){
          s16x8 a0 = *(const s16x8*)(Ab + ks*32);
          s16x8 a1 = *(const s16x8*)(Ab + 16*KP + ks*32);
          #pragma unroll
          for (int g = 0; g < 3; ++g){
            s16x8 bf = *(const s16x8*)((const char*)sW1 + (g*16 + lr)*1024
                        + ((ks*64 + lk*16) ^ ((lr & 7) << 4)));
            acc[0][g] = __builtin_amdgcn_mfma_f32_16x16x32_bf16(a0, bf, acc[0][g], 0, 0, 0);
            acc[1][g] = __builtin_amdgcn_mfma_f32_16x16x32_bf16(a1, bf, acc[1][g], 0, 0, 0);
          }
        }
      }

      const int h = c0 + lr;
      const float gbr = g_bhh[0*KP + h];
      const float gbz = g_bhh[1*KP + h];
      const float gbn = g_bhh[2*KP + h];
      #pragma unroll
      for (int rr = 0; rr < 2; ++rr){
        #pragma unroll
        for (int r = 0; r < 4; ++r){
          const int row = rb + (rf0 + rr)*16 + lk*4 + r;
          const int t = node_types[row*MAXN + v];
          const float gir = g_giT[(t*3 + 0)*KP + h];
          const float giz = g_giT[(t*3 + 1)*KP + h];
          const float gin = g_giT[(t*3 + 2)*KP + h];
          const float rg = sigm(gir + acc[rr][0][r] + gbr);
          const float zg = sigm(giz + acc[rr][1][r] + gbz);
          const float ng = tanh_f(gin + rg*(acc[rr][2][r] + gbn));
          const float hp = (v > 0) ? b2f(g_Hin[(size_t)row*KP + h]) : 0.f;
          const float hv = (1.f - zg)*ng + zg*hp;
          g_Hv[(size_t)row*KP + h] = (h < HS) ? f2b(hv) : (ushort)0;
        }
      }
    }
    GROUP_BARRIER();   // Hv complete for the stripe

    if (v < MAXN - 1){
      // ============ phase B: GEMM2 (Wg/Wm own 16 cols) + gated + gather ============
      {
        f32x4 acc[2][2];
        #pragma unroll
        for (int rr = 0; rr < 2; ++rr)
          #pragma unroll
          for (int s = 0; s < 2; ++s) acc[rr][s] = (f32x4){0.f,0.f,0.f,0.f};

        const ushort* Ab = g_Hv + (size_t)(rb + rf0*16 + lr)*KP + lk*8;
        #pragma unroll 4
        for (int ks = 0; ks < 16; ++ks){
          s16x8 a0 = *(const s16x8*)(Ab + ks*32);
          s16x8 a1 = *(const s16x8*)(Ab + 16*KP + ks*32);
          s16x8 b0 = *(const s16x8*)((const char*)sW2 + (0*16 + lr)*1024
                      + ((ks*64 + lk*16) ^ ((lr & 7) << 4)));
          s16x8 b1 = *(const s16x8*)((const char*)sW2 + (16 + lr)*1024
                      + ((ks*64 + lk*16) ^ (((16 + lr) & 7) << 4)));
          acc[0][0] = __builtin_amdgcn_mfma_f32_16x16x32_bf16(a0, b0, acc[0][0], 0, 0, 0);
          acc[0][1] = __builtin_amdgcn_mfma_f32_16x16x32_bf16(a0, b1, acc[0][1], 0, 0, 0);
          acc[1][0] = __builtin_amdgcn_mfma_f32_16x16x32_bf16(a1, b0, acc[1][0], 0, 0, 0);
          acc[1][1] = __builtin_amdgcn_mfma_f32_16x16x32_bf16(a1, b1, acc[1][1], 0, 0, 0);
        }

        const int h = c0 + lr;
        const float bgh = g_bgt[h] + g_wgid[v*KP + h];
        const float bmh = g_wmid[v*KP + h];
        #pragma unroll
        for (int rr = 0; rr < 2; ++rr){
          #pragma unroll
          for (int r = 0; r < 4; ++r){
            const int lrow = (rf0 + rr)*16 + lk*4 + r;
            const int row = rb + lrow;
            const float sg = sigm(acc[rr][0][r] + bgh);
            const float mg = acc[rr][1][r] + bmh;
            float gv = sg * mg;
            if (h >= HS) gv = 0.f;
            const ushort gvb = f2b(gv);
            g_gated[((size_t)row*MAXN + v)*KP + h] = gvb;
            sGt[lrow*16 + lr] = gvb;
          }
        }
      }
      __syncthreads();

      {
        // gather next Hin: 512 threads = 256 rows x 2 col-halves (8 cols, 16B)
        const int l    = tid >> 1;
        const int half = tid & 1;
        const int row  = rb + l;
        const int hb   = c0 + half*8;
        unsigned m = g_adjm[row*MAXN + v + 1];
        float a8[8] = {0.f,0.f,0.f,0.f,0.f,0.f,0.f,0.f};
        while (m){
          const int n = __builtin_ctz(m); m &= m - 1;
          s16x8 x;
          if (n == v) x = *(const s16x8*)(sGt + l*16 + half*8);
          else        x = *(const s16x8*)(g_gated + ((size_t)row*MAXN + n)*KP + hb);
          #pragma unroll
          for (int j = 0; j < 8; ++j) a8[j] += b2f((ushort)x[j]);
        }
        s16x8 o;
        #pragma unroll
        for (int j = 0; j < 8; ++j) o[j] = (short)f2b(a8[j]);
        *(s16x8*)(g_Hin + (size_t)row*KP + hb) = o;
      }
      GROUP_BARRIER();   // Hin complete for the stripe
    } else {
      // ============ final: mu/logvar = Hv(31) @ [W1;W2]^T + b ============
      if (w < 4){
        const int rf = J & 15;       // row-fragment of this group's stripe
        const int cf = (J >> 4)*4 + w;
        if (cf < 7){
          const ushort* Ab = g_Hv + (size_t)(rb + rf*16 + lr)*KP + lk*8;
          const ushort* Bb = g_Wf + (size_t)(cf*16 + lr)*KP + lk*8;
          f32x4 acc = (f32x4){0.f,0.f,0.f,0.f};
          #pragma unroll 4
          for (int ks = 0; ks < 16; ++ks){
            s16x8 a0 = *(const s16x8*)(Ab + ks*32);
            s16x8 b0 = *(const s16x8*)(Bb + ks*32);
            acc = __builtin_amdgcn_mfma_f32_16x16x32_bf16(a0, b0, acc, 0, 0, 0);
          }
          const int j2 = cf*16 + lr;
          #pragma unroll
          for (int r = 0; r < 4; ++r){
            const int row = rb + rf*16 + lk*4 + r;
            const float val = acc[r] + g_bias[j2];
            if (j2 < 56)       out[(size_t)row*56 + j2] = val;
            else if (j2 < 112) out[(size_t)NB*56 + (size_t)row*56 + (j2 - 56)] = val;
          }
        }
      }
    }
  }
}

extern "C" void kernel_launch(void* const* d_in, const int* in_sizes, int n_in,
                              void* d_out, int out_size, void* d_ws, size_t ws_size,
                              hipStream_t stream){
  const int*   node_types = (const int*)d_in[0];
  const void*  adj        = (const void*)d_in[1];
  const float* W_ih       = (const float*)d_in[2];
  const float* W_hh       = (const float*)d_in[3];
  const float* b_ih       = (const float*)d_in[4];
  const float* b_hh       = (const float*)d_in[5];
  const float* Wg         = (const float*)d_in[6];
  const float* bg         = (const float*)d_in[7];
  const float* Wm         = (const float*)d_in[8];
  const float* W1         = (const float*)d_in[9];
  const float* b1         = (const float*)d_in[10];
  const float* W2         = (const float*)d_in[11];
  const float* b2         = (const float*)d_in[12];
  float* out = (float*)d_out;

  const int NPREP1 = 3*KP*KP + 2*KP*KP + 128*KP;
  const int NPREP2 = NVT*3*KP + 3*KP + 2*MAXN*KP + KP + 128 + NB*MAXN;

  detect_adj  <<<1, 256, 0, stream>>>(adj);
  prep_weights<<<(NPREP1 + 255)/256, 256, 0, stream>>>(W_hh, Wg, Wm, W1, W2);
  prep_tables <<<(NPREP2 + 255)/256, 256, 0, stream>>>(W_ih, b_ih, b_hh, Wg, Wm, bg, b1, b2, adj);

  void* kargs[] = { (void*)&node_types, (void*)&out };
  hipLaunchCooperativeKernel((void*)k_steps, dim3(256), dim3(512), kargs, 0, stream);
}